// Round 9
// baseline (234.283 us; speedup 1.0000x reference)
//
#include <hip/hip_runtime.h>
#include <hip/hip_bf16.h>

#define DMODEL 1024
#define NHEAD  16
#define DHEAD  64
#define BATCH  2
#define LQ     2048
#define LV     2048
#define ROWS   (BATCH*LQ)          // 4096 total rows
#define WELEMS (DMODEL*DMODEL)     // 1 Mi elements per weight matrix
#define BH     (BATCH*NHEAD)       // 32

typedef short bf16x8 __attribute__((ext_vector_type(8)));   // 8 bf16 (4 VGPRs)
typedef float f32x4  __attribute__((ext_vector_type(4)));   // MFMA C/D

__device__ __forceinline__ float bf2f(unsigned short s) {
    union { unsigned u; float f; } v; v.u = ((unsigned)s) << 16;
    return v.f;
}
// packed RNE f32x2 -> bf16x2 (v_cvt_pk_bf16_f32 on gfx950)
__device__ __forceinline__ unsigned pk_bf(float a, float b) {
    union { __hip_bfloat162 h; unsigned u; } c;
    c.h = __float22bfloat162_rn(make_float2(a, b));
    return c.u;
}

// async 16B global -> LDS (wave-uniform LDS base + lane*16)
__device__ __forceinline__ void cp16_g2l(const void* g, void* l) {
    __builtin_amdgcn_global_load_lds(
        (const __attribute__((address_space(1))) void*)g,
        (__attribute__((address_space(3))) void*)l,
        16, 0, 0);
}

// scale folded into qs: exp(qk/8) = exp2(qk * 0.125 * log2(e))
#define QSCALE (0.125f * 1.4426950408889634f)

// ---------------- prep v2: flat grid, exact block counts (unchanged R7) ----------------
#define PREP_WBLK (5 * 256)            // 1280
#define PREP_NBLK (PREP_WBLK + 3 * ROWS / 4)   // 1280 + 3072 = 4352

__global__ __launch_bounds__(256) void prep_kernel(
    const float* q, const float* k, const float* v,
    const float* qg, const float* qb, const float* kvg, const float* kvb,
    const float* Wq, const float* Wk, const float* Wv, const float* Wg, const float* Wo,
    unsigned short* qn, unsigned short* kn, unsigned short* vn, unsigned short* wb)
{
    int bx = blockIdx.x, tid = threadIdx.x;
    if (bx < PREP_WBLK) {
        int z = bx >> 8;                       // weight index 0..4
        const float* srcs[5] = {Wq, Wk, Wv, Wg, Wo};
        size_t base = (size_t)(bx & 255) * 4096;
        const float* s = srcs[z] + base;
        unsigned short* d = wb + (size_t)z * WELEMS + base;
        #pragma unroll
        for (int u = 0; u < 4; ++u) {
            int i = u * 1024 + tid * 4;
            float4 x = *(const float4*)(s + i);
            *(uint2*)(d + i) = make_uint2(pk_bf(x.x, x.y), pk_bf(x.z, x.w));
        }
        return;
    }
    int wave = tid >> 6, lane = tid & 63;
    int gr = (bx - PREP_WBLK) * 4 + wave;
    int tz = gr >> 12, row = gr & 4095;
    const float *x, *gp, *bp; unsigned short* o;
    if      (tz == 0) { x = q; gp = qg;  bp = qb;  o = qn; }
    else if (tz == 1) { x = k; gp = kvg; bp = kvb; o = kn; }
    else              { x = v; gp = kvg; bp = kvb; o = vn; }
    const float* xr = x + (size_t)row * DMODEL;

    float4 xv[4];
    float s = 0.f, sq = 0.f;
    #pragma unroll
    for (int u = 0; u < 4; ++u) {
        xv[u] = *(const float4*)(xr + u * 256 + lane * 4);
        s  += xv[u].x + xv[u].y + xv[u].z + xv[u].w;
        sq += xv[u].x*xv[u].x + xv[u].y*xv[u].y + xv[u].z*xv[u].z + xv[u].w*xv[u].w;
    }
    #pragma unroll
    for (int off = 1; off < 64; off <<= 1) { s += __shfl_xor(s, off); sq += __shfl_xor(sq, off); }
    float mu  = s * (1.0f / DMODEL);
    float var = sq * (1.0f / DMODEL) - mu * mu;
    float inv = rsqrtf(var + 1e-5f);

    unsigned short* orow = o + (size_t)row * DMODEL;
    #pragma unroll
    for (int u = 0; u < 4; ++u) {
        int col = u * 256 + lane * 4;
        float4 gv = *(const float4*)(gp + col);
        float4 bv = *(const float4*)(bp + col);
        float r0 = (xv[u].x - mu) * inv * gv.x + bv.x;
        float r1 = (xv[u].y - mu) * inv * gv.y + bv.y;
        float r2 = (xv[u].z - mu) * inv * gv.z + bv.z;
        float r3 = (xv[u].w - mu) * inv * gv.w + bv.w;
        *(uint2*)(orow + col) = make_uint2(pk_bf(r0, r1), pk_bf(r2, r3));
    }
}

// ------------- unified 128x128 GEMM core, BK=64, counted vmcnt, 2 blocks/CU -------------
// The f32out-v2 structure generalized: 4 waves (2x2), per-wave 64x64 = acc[4][4].
// Per K-tile: {stage tile t+1 (8 gload_lds) -> vmcnt(8) (drains tile t, keeps
// t+1 in flight; never 0 till tail) -> bar -> 16 ds_read_b128 + 32 MFMA
// (setprio) -> bar}.  LDS 64 KiB total -> 2 BLOCKS/CU: the co-resident block's
// MFMA covers this block's barrier/drain stalls (m114 cross-wave co-scheduling
// — the TLP every 1-block/CU 256^2 variant lacked; 5 schedule variants all
// pinned at ~25% MfmaUtil without it).
// Swizzle (both-sides XOR): linear gload_lds dest + pre-swizzled SOURCE
// col16=(l&7)^(l>>3); ds_read elem ^ ((L&7)<<3) -> 0 bank conflicts (measured).
// Per-element K accumulation order identical to all previous versions
// (ascending 64-tiles, (ks0,ks1) pairs) -> bit-identical outputs.
// MODE 0: bf16*scale  MODE 1: sigmoid(x+bias) bf16  MODE 2: f32  MODE 3: vt store.
template<int MODE>
__device__ __forceinline__ void gemm128_core(
    const unsigned short* A, const unsigned short* Bw,
    unsigned short* Obf, float* Of32, const float* bias, float scale,
    unsigned short* Al, unsigned short* Bl, int bm, int bn)
{
    int tid = threadIdx.x;
    int w = tid >> 6, l = tid & 63, quad = l >> 4, L = l & 15;
    int wm = w >> 1, wn = w & 1;

    int c16 = (l & 7) ^ (l >> 3);          // pre-swizzled source col16
    const unsigned short* gAs = A  + (size_t)(bm * 128 + w * 8 + (l >> 3)) * DMODEL + c16 * 8;
    const unsigned short* gBs = Bw + (size_t)(bn * 128 + w * 8 + (l >> 3)) * DMODEL + c16 * 8;
    int dstE = w * 512;                    // elem base within a 32-row line

    // stage tile t (4 instrs = 4 x 32-row lines) into slot t&1
    #define STG4(t, gp, lp) do { const unsigned short* s_ = (gp) + (t) * 64;  \
        unsigned short* d_ = (lp) + ((t) & 1) * 8192 + dstE;                  \
        cp16_g2l(s_,               d_);                                       \
        cp16_g2l(s_ + 32 * DMODEL, d_ + 2048);                                \
        cp16_g2l(s_ + 64 * DMODEL, d_ + 4096);                                \
        cp16_g2l(s_ + 96 * DMODEL, d_ + 6144); } while (0)

    int sw = (L & 7) << 3;
    int o0 = (quad * 8) ^ sw;
    int o1 = (32 + quad * 8) ^ sw;

    f32x4 acc[4][4];
    #pragma unroll
    for (int i = 0; i < 4; ++i)
        #pragma unroll
        for (int j = 0; j < 4; ++j) acc[i][j] = (f32x4){0.f, 0.f, 0.f, 0.f};

    STG4(0, gAs, Al); STG4(0, gBs, Bl);

    const int NT = DMODEL / 64;   // 16
    for (int t = 0; t < NT; ++t) {
        if (t + 1 < NT) {
            STG4(t + 1, gAs, Al); STG4(t + 1, gBs, Bl);
            asm volatile("s_waitcnt vmcnt(8)" ::: "memory");   // drains tile t
        } else {
            asm volatile("s_waitcnt vmcnt(0)" ::: "memory");
        }
        __builtin_amdgcn_s_barrier();

        const unsigned short* Ab = Al + (t & 1) * 8192 + (wm * 64) * 64;
        const unsigned short* Bb = Bl + (t & 1) * 8192 + (wn * 64) * 64;
        bf16x8 a0[4], a1[4], b0[4], b1[4];
        #pragma unroll
        for (int j = 0; j < 4; ++j) {
            b0[j] = *(const bf16x8*)&Bb[(j * 16 + L) * 64 + o0];
            b1[j] = *(const bf16x8*)&Bb[(j * 16 + L) * 64 + o1];
        }
        #pragma unroll
        for (int i = 0; i < 4; ++i) {
            a0[i] = *(const bf16x8*)&Ab[(i * 16 + L) * 64 + o0];
            a1[i] = *(const bf16x8*)&Ab[(i * 16 + L) * 64 + o1];
        }
        __builtin_amdgcn_s_setprio(1);
        #pragma unroll
        for (int i = 0; i < 4; ++i)
            #pragma unroll
            for (int j = 0; j < 4; ++j) {
                if (MODE == 3) {
                    acc[i][j] = __builtin_amdgcn_mfma_f32_16x16x32_bf16(a0[i], b0[j], acc[i][j], 0, 0, 0);
                    acc[i][j] = __builtin_amdgcn_mfma_f32_16x16x32_bf16(a1[i], b1[j], acc[i][j], 0, 0, 0);
                } else {
                    acc[i][j] = __builtin_amdgcn_mfma_f32_16x16x32_bf16(b0[j], a0[i], acc[i][j], 0, 0, 0);
                    acc[i][j] = __builtin_amdgcn_mfma_f32_16x16x32_bf16(b1[j], a1[i], acc[i][j], 0, 0, 0);
                }
            }
        __builtin_amdgcn_s_setprio(0);
        __builtin_amdgcn_s_barrier();
    }
    #undef STG4

    // ---- epilogue (layouts verified in R1-era 128^2 cores) ----
    #pragma unroll
    for (int i = 0; i < 4; ++i) {
        #pragma unroll
        for (int j = 0; j < 4; ++j) {
            f32x4 a = acc[i][j];
            if (MODE == 3) {
                int gcol  = bn * 128 + wn * 64 + j * 16 + L;        // (h, d)
                int grow0 = bm * 128 + wm * 64 + i * 16 + quad * 4; // 4 consecutive keys
                int b = grow0 >> 11, key0 = grow0 & 2047;
                int h = gcol >> 6,   dd   = gcol & 63;
                uint2 o = make_uint2(pk_bf(a[0], a[1]), pk_bf(a[2], a[3]));
                *(uint2*)&Obf[(((size_t)(b * NHEAD + h) * DHEAD + dd) << 11) + key0] = o;
            } else {
                int grow  = bm * 128 + wm * 64 + i * 16 + L;
                int gcol0 = bn * 128 + wn * 64 + j * 16 + quad * 4; // 4 consecutive cols
                size_t idx = (size_t)grow * DMODEL + gcol0;
                if (MODE == 2) {
                    *(f32x4*)&Of32[idx] = a;
                } else if (MODE == 0) {
                    uint2 o = make_uint2(pk_bf(a[0] * scale, a[1] * scale),
                                         pk_bf(a[2] * scale, a[3] * scale));
                    *(uint2*)&Obf[idx] = o;
                } else {
                    float4 bv = *(const float4*)&bias[gcol0];
                    float s0 = 1.0f / (1.0f + __expf(-(a[0] + bv.x)));
                    float s1 = 1.0f / (1.0f + __expf(-(a[1] + bv.y)));
                    float s2 = 1.0f / (1.0f + __expf(-(a[2] + bv.z)));
                    float s3 = 1.0f / (1.0f + __expf(-(a[3] + bv.w)));
                    *(uint2*)&Obf[idx] = make_uint2(pk_bf(s0, s1), pk_bf(s2, s3));
                }
            }
        }
    }
}

// 1024 blocks x 256 thr, 2 blocks/CU.  f = blockIdx: xcd = f&7 (HW round-robin),
// r = f>>3.  z = r>>5 (dispatch-major: all z=0 blocks first -> each XCD streams
// one 2 MB B panel at a time); s = r&31: bm = ((s>>3)<<3)|xcd (XCD owns 4 A-row
// panels per z), bn = s&7.  Per-XCD L2 working set: B panel 2 MB + 4 A panels
// 1 MB = 3 MB < 4 MB.
__global__ __launch_bounds__(256, 2) void gemm128_kernel(
    const unsigned short* qn, const unsigned short* kn, const unsigned short* vn,
    const unsigned short* wb,
    unsigned short* qs, unsigned short* kkp, unsigned short* vt, unsigned short* gate,
    const float* bg)
{
    __shared__ __align__(16) unsigned short Al[2 * 128 * 64];   // 32 KiB
    __shared__ __align__(16) unsigned short Bl[2 * 128 * 64];   // 32 KiB
    int f = blockIdx.x, xcd = f & 7, r = f >> 3;
    int z = r >> 5, s = r & 31;
    int bm = ((s >> 3) << 3) | xcd;
    int bn = s & 7;
    switch (z) {
        case 0:  gemm128_core<0>(qn, wb + 0 * WELEMS, qs,   nullptr, nullptr, QSCALE, Al, Bl, bm, bn); break;
        case 1:  gemm128_core<0>(kn, wb + 1 * WELEMS, kkp,  nullptr, nullptr, 1.0f,   Al, Bl, bm, bn); break;
        case 2:  gemm128_core<3>(vn, wb + 2 * WELEMS, vt,   nullptr, nullptr, 1.0f,   Al, Bl, bm, bn); break;
        default: gemm128_core<1>(qn, wb + 3 * WELEMS, gate, nullptr, bg,      1.0f,   Al, Bl, bm, bn); break;
    }
}

// XCD swizzle for a (8 bn, 32 bm) tile grid of 128^2 tiles (Wo GEMM).
__device__ __forceinline__ void xcd_map(int& bm, int& bn) {
    int f = blockIdx.y * 8 + blockIdx.x;   // 0..255
    int xcd = f & 7, s = f >> 3;           // s: 0..31
    bn = s & 7;
    bm = ((s >> 3) << 3) | xcd;
}

__global__ __launch_bounds__(256, 2) void gemm_f32out_kernel(
    const unsigned short* A, const unsigned short* Bw, float* O)
{
    __shared__ __align__(16) unsigned short Al[2 * 128 * 64];   // 32 KiB
    __shared__ __align__(16) unsigned short Bl[2 * 128 * 64];   // 32 KiB
    int bm, bn; xcd_map(bm, bn);
    gemm128_core<2>(A, Bw, nullptr, O, nullptr, 1.0f, Al, Bl, bm, bn);
}

// ---------------- flash attention + gate, full KV (unchanged from R6) ----------------
__global__ __launch_bounds__(256, 4) void attn_kernel(
    const unsigned short* qs, const unsigned short* kk, const unsigned short* vt,
    const unsigned short* gate, unsigned short* yg)
{
    __shared__ __align__(16) unsigned short Kl[2 * 64 * 64];   // 16 KB dbuf
    __shared__ __align__(16) unsigned short Vl[3 * 64 * 64];   // 24 KB ring-3

    int tid  = threadIdx.x;
    int wave = tid >> 6, lane = tid & 63, quad = lane >> 4, L = lane & 15;

    int f  = blockIdx.y * 32 + blockIdx.x;        // 0..1023
    int bh = (f & 7) * 4 + ((f >> 3) & 3);
    int qt = f >> 5;                              // 0..31
    int bb = bh >> 4, h = bh & 15;
    int q0 = qt * 64;

    const unsigned short* Qb =
        qs + ((size_t)(bb * LQ + q0 + wave * 16 + L)) * DMODEL + h * DHEAD;
    bf16x8 aq0 = *(const bf16x8*)(Qb + quad * 8);
    bf16x8 aq1 = *(const bf16x8*)(Qb + 32 + quad * 8);

    f32x4 acc[4];
    #pragma unroll
    for (int nt = 0; nt < 4; ++nt) acc[nt] = (f32x4){0.f, 0.f, 0.f, 0.f};
    f32x4 lacc = (f32x4){0.f, 0.f, 0.f, 0.f};
    bf16x8 ones;
    #pragma unroll
    for (int j = 0; j < 8; ++j) ones[j] = (short)0x3F80;   // bf16 1.0

    int rloc = lane >> 3;
    int c16  = (lane & 7) ^ rloc;
    int key0 = (wave & 1) * 32 + (rloc >> 2) * 8 + (wave >> 1) * 4 + (rloc & 3);

    const unsigned short* gK = kk + (size_t)bb * LV * DMODEL + h * DHEAD
                                  + (size_t)key0 * DMODEL + c16 * 8;
    const unsigned short* gV = vt + ((size_t)((bb * NHEAD + h) * DHEAD
                                  + wave * 16 + rloc)) * LV + c16 * 8;
    char* KlB = (char*)Kl;
    char* VlB = (char*)Vl;
    int dst0 = wave * 2048;

    int sl0 = (quad ^ (L & 7)) * 8;

    cp16_g2l(gK,               KlB + dst0);
    cp16_g2l(gK + 16 * DMODEL, KlB + dst0 + 1024);
    cp16_g2l(gV,               VlB + dst0);
    cp16_g2l(gV + 8 * LV,      VlB + dst0 + 1024);
    __syncthreads();
    gK += 64 * DMODEL; gV += 64;
    cp16_g2l(gK,               KlB + 8192 + dst0);
    cp16_g2l(gK + 16 * DMODEL, KlB + 8192 + dst0 + 1024);
    cp16_g2l(gV,               VlB + 8192 + dst0);
    cp16_g2l(gV + 8 * LV,      VlB + 8192 + dst0 + 1024);

    bf16x8 pap0, pap1;

    {
        const unsigned short* Kb = Kl;
        f32x4 zz[4];
        __builtin_amdgcn_s_setprio(1);
        #pragma unroll
        for (int kt = 0; kt < 4; ++kt) {
            bf16x8 bk0 = *(const bf16x8*)&Kb[(kt * 16 + L) * 64 + sl0];
            bf16x8 bk1 = *(const bf16x8*)&Kb[(kt * 16 + L) * 64 + (sl0 ^ 32)];
            f32x4 z = (f32x4){0.f, 0.f, 0.f, 0.f};
            z = __builtin_amdgcn_mfma_f32_16x16x32_bf16(bk0, aq0, z, 0, 0, 0);
            z = __builtin_amdgcn_mfma_f32_16x16x32_bf16(bk1, aq1, z, 0, 0, 0);
            zz[kt] = z;
        }
        __builtin_amdgcn_s_setprio(0);
        union { unsigned u[4]; bf16x8 h; } pa0, pa1;
        pa0.u[0] = pk_bf(__builtin_amdgcn_exp2f(zz[0][0]), __builtin_amdgcn_exp2f(zz[0][1]));
        pa0.u[1] = pk_bf(__builtin_amdgcn_exp2f(zz[0][2]), __builtin_amdgcn_exp2f(zz[0][3]));
        pa0.u[2] = pk_bf(__builtin_amdgcn_exp2f(zz[2][0]), __builtin_amdgcn_exp2f(zz[2][1]));
        pa0.u[3] = pk_bf(__builtin_amdgcn_exp2f(zz[2][2]), __builtin_amdgcn_exp2f(zz[2][3]));
        pa1.u[0] = pk_bf(__builtin_amdgcn_exp2f(zz[1][0]), __builtin_amdgcn_exp2f(zz[1][1]));
        pa1.u[1] = pk_bf(__builtin_amdgcn_exp2f(zz[1][2]), __builtin_amdgcn_exp2f(zz[1][3]));
        pa1.u[2] = pk_bf(__builtin_amdgcn_exp2f(zz[3][0]), __builtin_amdgcn_exp2f(zz[3][1]));
        pa1.u[3] = pk_bf(__builtin_amdgcn_exp2f(zz[3][2]), __builtin_amdgcn_exp2f(zz[3][3]));
        pap0 = pa0.h; pap1 = pa1.h;
    }

    const int NT = LV / 64;   // 32
    int vs = 2;
    int vr = 0;
    for (int t = 1; t < NT; ++t) {
        __syncthreads();
        if (t + 1 < NT) {
            gK += 64 * DMODEL; gV += 64;
            int kb = ((t + 1) & 1) * 8192;
            cp16_g2l(gK,               KlB + kb + dst0);
            cp16_g2l(gK + 16 * DMODEL, KlB + kb + dst0 + 1024);
            int vb_ = vs * 8192;
            cp16_g2l(gV,               VlB + vb_ + dst0);
            cp16_g2l(gV + 8 * LV,      VlB + vb_ + dst0 + 1024);
            vs = (vs == 2) ? 0 : vs + 1;
        }
        const unsigned short* Vb = Vl + vr * 4096;
        vr = (vr == 2) ? 0 : vr + 1;
        const unsigned short* Kb = Kl + (t & 1) * 4096;

        bf16x8 vf0[4], vf1[4];
        #pragma unroll
        for (int nt = 0; nt < 4; ++nt) {
            vf0[nt] = *(const bf16x8*)&Vb[(nt * 16 + L) * 64 + sl0];
            vf1[nt] = *(const bf16x8*)&Vb[(nt * 16 + L) * 64 + (sl0 ^ 32)];
        }
        bf16x8 kf0[4], kf1[4];
        #pragma unroll
        for (int kt = 0; kt < 4; ++kt) {
            kf0[kt] = *(const bf16x8*)&Kb[(kt * 16 + L) * 64 + sl0];
            kf1[kt] = *(const bf16x8*)&Kb[(kt * 16 + L) * 64 + (sl0 ^ 32)];
        }

        __builtin_amdgcn_s_setprio(1);
        lacc = __builtin_amdgcn_mfma_f32_16x16x32_bf16(ones, pap0, lacc, 0, 0, 0);
        lacc = __builtin_amdgcn_mfma_f32_16x16x32_bf16(ones, pap1, lacc, 0, 0, 0);
        #pragma unroll
        for (int nt = 0; nt < 4; ++nt) {
            acc[nt] = __builtin_amdgcn_mfma_f32_16x16x32_bf16(vf0[nt], pap0, acc[nt], 0, 0, 0);
            acc[nt] = __builtin_amdgcn_mfma_f32_16x16x32_bf16(vf1[nt], pap1, acc[nt], 0, 0, 0);
        }
        f32x4 zz[4];
        #pragma unroll
        for (int kt = 0; kt < 4; ++kt) {
            f32x4 z = (f32x4){0.f, 0.f, 0.f, 0.f};
            z = __builtin_amdgcn_mfma_f32_16x16x32_bf16(kf0[kt], aq0, z, 0, 0, 0);
            z = __builtin_amdgcn_mfma_f32_16x16x32_bf16(kf1[kt], aq1, z, 0, 0, 0);
            zz[kt] = z;
        }
        __builtin_amdgcn_s_setprio(0);
        union { unsigned u[4]; bf16x8 h; } pa0, pa1;
        pa0.u[0] = pk_bf(__builtin_amdgcn_exp2f(zz[0][0]), __builtin_amdgcn_exp2f(zz[0][1]));
        pa0.u[1] = pk_bf(__builtin_amdgcn_exp2f(zz[0][2]), __builtin_amdgcn_exp2f(zz[0][3]));
        pa0.u[2] = pk_bf(__builtin_amdgcn_exp2f(zz[2][0]), __builtin_amdgcn_exp2f(zz[2][1]));
        pa0.u[3] = pk_bf(__builtin_amdgcn_exp2f(zz[2][2]), __builtin_amdgcn_exp2f(zz[2][3]));
        pa1.u[0] = pk_bf(__builtin_amdgcn_exp2f(zz[1][0]), __builtin_amdgcn_exp2f(zz[1][1]));
        pa1.u[1] = pk_bf(__builtin_amdgcn_exp2f(zz[1][2]), __builtin_amdgcn_exp2f(zz[1][3]));
        pa1.u[2] = pk_bf(__builtin_amdgcn_exp2f(zz[3][0]), __builtin_amdgcn_exp2f(zz[3][1]));
        pa1.u[3] = pk_bf(__builtin_amdgcn_exp2f(zz[3][2]), __builtin_amdgcn_exp2f(zz[3][3]));
        pap0 = pa0.h; pap1 = pa1.h;
    }

    {
        const unsigned short* Vb = Vl + 1 * 4096;
        bf16x8 vf0[4], vf1[4];
        #pragma unroll
        for (int nt = 0; nt < 4; ++nt) {
            vf0[nt] = *(const bf16x8*)&Vb[(nt * 16 + L) * 64 + sl0];
            vf1[nt] = *(const bf16x8*)&Vb[(nt * 16 + L) * 64 + (sl0 ^ 32)];
        }
        lacc = __builtin_amdgcn_mfma_f32_16x16x32_bf16(ones, pap0, lacc, 0, 0, 0);
        lacc = __builtin_amdgcn_mfma_f32_16x16x32_bf16(ones, pap1, lacc, 0, 0, 0);
        #pragma unroll
        for (int nt = 0; nt < 4; ++nt) {
            acc[nt] = __builtin_amdgcn_mfma_f32_16x16x32_bf16(vf0[nt], pap0, acc[nt], 0, 0, 0);
            acc[nt] = __builtin_amdgcn_mfma_f32_16x16x32_bf16(vf1[nt], pap1, acc[nt], 0, 0, 0);
        }
    }

    float inv_l = 1.0f / lacc[0];
    size_t rb = ((size_t)(bb * LQ + q0 + wave * 16 + L)) * DMODEL + h * DHEAD;
    #pragma unroll
    for (int nt = 0; nt < 4; ++nt) {
        size_t idx = rb + nt * 16 + quad * 4;
        ushort4 g = *(const ushort4*)&gate[idx];
        float y0 = acc[nt][0] * inv_l * bf2f(g.x);
        float y1 = acc[nt][1] * inv_l * bf2f(g.y);
        float y2 = acc[nt][2] * inv_l * bf2f(g.z);
        float y3 = acc[nt][3] * inv_l * bf2f(g.w);
        *(uint2*)&yg[idx] = make_uint2(pk_bf(y0, y1), pk_bf(y2, y3));
    }
}

// ---------------- host launcher ----------------
extern "C" void kernel_launch(void* const* d_in, const int* in_sizes, int n_in,
                              void* d_out, int out_size, void* d_ws, size_t ws_size,
                              hipStream_t stream)
{
    const float* q      = (const float*)d_in[0];
    const float* k      = (const float*)d_in[1];
    const float* v      = (const float*)d_in[2];
    const float* qln_g  = (const float*)d_in[3];
    const float* qln_b  = (const float*)d_in[4];
    const float* kvln_g = (const float*)d_in[5];
    const float* kvln_b = (const float*)d_in[6];
    const float* Wq     = (const float*)d_in[7];
    const float* Wk     = (const float*)d_in[8];
    const float* Wv     = (const float*)d_in[9];
    const float* Wg     = (const float*)d_in[10];
    const float* bg     = (const float*)d_in[11];
    const float* Wo     = (const float*)d_in[12];
    float* out = (float*)d_out;

    const size_t T8 = (size_t)ROWS * DMODEL * 2;   // 8 MiB per [4096,1024] bf16 tensor
    char* ws = (char*)d_ws;
    unsigned short* qn   = (unsigned short*)(ws + 0 * T8);
    unsigned short* kn   = (unsigned short*)(ws + 1 * T8);
    unsigned short* vn   = (unsigned short*)(ws + 2 * T8);
    unsigned short* qs   = (unsigned short*)(ws + 3 * T8);
    unsigned short* kkp  = (unsigned short*)(ws + 4 * T8);
    unsigned short* vt   = (unsigned short*)(ws + 5 * T8);  // [b][h][64][2048]
    unsigned short* gate = (unsigned short*)(ws + 6 * T8);
    unsigned short* yg   = (unsigned short*)(ws + 7 * T8);
    unsigned short* wb   = (unsigned short*)(ws + 8 * T8);  // 5 x 2 MiB bf16 weights

    prep_kernel<<<dim3(PREP_NBLK), 256, 0, stream>>>(
        q, k, v, qln_g, qln_b, kvln_g, kvln_b, Wq, Wk, Wv, Wg, Wo, qn, kn, vn, wb);
    gemm128_kernel<<<dim3(1024), 256, 0, stream>>>(
        qn, kn, vn, wb, qs, kkp, vt, gate, bg);
    attn_kernel<<<dim3(32, 32), 256, 0, stream>>>(qs, kkp, vt, gate, yg);
    gemm_f32out_kernel<<<dim3(DMODEL / 128, ROWS / 128), 256, 0, stream>>>(yg, wb + 4 * WELEMS, out);
}